// Round 4
// baseline (519.320 us; speedup 1.0000x reference)
//
#include <hip/hip_runtime.h>
#include <hip/hip_bf16.h>
#include <math.h>

#define N_SEQ  2048
#define DMODEL 2048
#define NHEAD  16
#define HDIM   128
#define QKV_LD 6144   // 3*DMODEL

typedef __attribute__((ext_vector_type(8))) short bf16x8;
typedef __attribute__((ext_vector_type(4))) float f32x4;

__device__ __forceinline__ ushort f2bf(float x) {
    union { float f; unsigned u; } v; v.f = x;
    unsigned r = (v.u + 0x7fffu + ((v.u >> 16) & 1u)) >> 16;
    return (ushort)r;
}
__device__ __forceinline__ float bf2f(ushort h) {
    union { unsigned u; float f; } v; v.u = ((unsigned)h) << 16;
    return v.f;
}

// ===========================================================================
// convert_split: fp32 [n] -> bf16 hi/lo same layout (vectorized float4)
// ===========================================================================
__global__ __launch_bounds__(256)
void convert_split(const float* __restrict__ in, ushort* __restrict__ oh,
                   ushort* __restrict__ ol, int n4)
{
    int i = blockIdx.x * 256 + threadIdx.x;
    if (i >= n4) return;
    float4 v = ((const float4*)in)[i];
    ushort4 h, l;
    h.x = f2bf(v.x); l.x = f2bf(v.x - bf2f(h.x));
    h.y = f2bf(v.y); l.y = f2bf(v.y - bf2f(h.y));
    h.z = f2bf(v.z); l.z = f2bf(v.z - bf2f(h.z));
    h.w = f2bf(v.w); l.w = f2bf(v.w - bf2f(h.w));
    ((ushort4*)oh)[i] = h;
    ((ushort4*)ol)[i] = l;
}

// ===========================================================================
// convert_split_t: fp32 [R][C] -> bf16 hi/lo transposed [C][R]
// ===========================================================================
__global__ __launch_bounds__(256)
void convert_split_t(const float* __restrict__ in, ushort* __restrict__ oh,
                     ushort* __restrict__ ol, int R, int C)
{
    __shared__ float T[64][65];
    const int t = threadIdx.x;
    const int c0 = blockIdx.x * 64, r0 = blockIdx.y * 64;
    #pragma unroll
    for (int p = 0; p < 4; ++p) {
        int r = (t >> 4) + p * 16;
        int c4 = (t & 15) * 4;
        float4 v = *(const float4*)&in[(size_t)(r0 + r) * C + c0 + c4];
        T[r][c4] = v.x; T[r][c4 + 1] = v.y; T[r][c4 + 2] = v.z; T[r][c4 + 3] = v.w;
    }
    __syncthreads();
    #pragma unroll
    for (int p = 0; p < 4; ++p) {
        int c = (t >> 4) + p * 16;
        int r4 = (t & 15) * 4;
        float f0 = T[r4][c], f1 = T[r4 + 1][c], f2 = T[r4 + 2][c], f3 = T[r4 + 3][c];
        ushort4 h, l;
        h.x = f2bf(f0); l.x = f2bf(f0 - bf2f(h.x));
        h.y = f2bf(f1); l.y = f2bf(f1 - bf2f(h.y));
        h.z = f2bf(f2); l.z = f2bf(f2 - bf2f(h.z));
        h.w = f2bf(f3); l.w = f2bf(f3 - bf2f(h.w));
        *(ushort4*)&oh[(size_t)(c0 + c) * R + r0 + r4] = h;
        *(ushort4*)&ol[(size_t)(c0 + c) * R + r0 + r4] = l;
    }
}

// ===========================================================================
// transpose_v: qkv_hi [2048][6144] cols 4096.. (= V bf16) -> vt [2048][2048]
// ===========================================================================
__global__ __launch_bounds__(256)
void transpose_v(const ushort* __restrict__ qkvh, ushort* __restrict__ vt)
{
    __shared__ ushort T[64][72];
    const int t = threadIdx.x;
    const int c0 = blockIdx.x * 64, n0 = blockIdx.y * 64;
    #pragma unroll
    for (int p = 0; p < 2; ++p) {
        int r = (t >> 3) + p * 32;
        int u = (t & 7) * 8;
        *(bf16x8*)&T[r][u] = *(const bf16x8*)&qkvh[(size_t)(n0 + r) * QKV_LD + 2 * DMODEL + c0 + u];
    }
    __syncthreads();
    #pragma unroll
    for (int p = 0; p < 2; ++p) {
        int d = (t >> 3) + p * 32;
        int ju = (t & 7) * 8;
        bf16x8 o;
        #pragma unroll
        for (int i = 0; i < 8; ++i) o[i] = (short)T[ju + i][d];
        *(bf16x8*)&vt[(size_t)(c0 + d) * N_SEQ + n0 + ju] = o;
    }
}

// ===========================================================================
// gemm_bf16x3_v2: 256x256 tile, BK=32, 512 thr (8 waves 2Mx4N, wave=128x64).
// C[M][N] = (Ah+Al)[M][K] @ (Bh+Bl)^T, B stored [N][K]. 3-term MFMA.
// LDS rows: [hi 64B | lo 64B] pitch 68 ushorts (136B) -> conflict-free reads
// and writes (bank-start (2r+4s)%32, distinct within 16-lane quarters).
// Register double-buffer: one raw barrier per K-step; global loads for tile
// i+2 fly across the barrier through the whole compute phase.
// ===========================================================================
#define GBM 256
#define GBN 256
#define GBK 32
#define GPITCH 68

template<bool BF16OUT>
__global__ __launch_bounds__(512, 2)
void gemm_bf16x3_v2(const ushort* __restrict__ Ah_g, const ushort* __restrict__ Al_g,
                    const ushort* __restrict__ Bh_g, const ushort* __restrict__ Bl_g,
                    ushort* __restrict__ Ch, ushort* __restrict__ Cl,
                    float* __restrict__ Cf, int M, int N, int K)
{
    __shared__ ushort bufA[2][GBM * GPITCH];
    __shared__ ushort bufB[2][GBN * GPITCH];

    const int t = threadIdx.x;
    const int l = t & 63;
    const int w = t >> 6;
    const int l15 = l & 15, kgr = l >> 4;
    const int wm = (w >> 2) * 128;     // wave row block (2 in M)
    const int wn = (w & 3) * 64;       // wave col block (4 in N)

    // XCD-aware bijective block swizzle (valid when nwg % 8 == 0)
    const int nbx = N / GBN, nby = M / GBM;
    const int nwg = nbx * nby;
    int flat = blockIdx.x + blockIdx.y * nbx;
    if ((nwg & 7) == 0) flat = (flat & 7) * (nwg >> 3) + (flat >> 3);
    const int bm = (flat / nbx) * GBM;
    const int bn = (flat % nbx) * GBN;

    // staging assignment: thread t owns row rA (A) / rA (B), half hA
    const int rA = t >> 1;             // 0..255
    const int hA = t & 1;              // 0=hi, 1=lo
    const ushort* gA = (hA ? Al_g : Ah_g) + (size_t)(bm + rA) * K;
    const ushort* gB = (hA ? Bl_g : Bh_g) + (size_t)(bn + rA) * K;

    bf16x8 stA[4], stB[4];
    auto load_regs = [&](int k0) {
        #pragma unroll
        for (int j = 0; j < 4; ++j) {
            stA[j] = *(const bf16x8*)(gA + k0 + j * 8);
            stB[j] = *(const bf16x8*)(gB + k0 + j * 8);
        }
    };
    auto write_lds = [&](int b) {
        #pragma unroll
        for (int j = 0; j < 4; ++j) {
            *(bf16x8*)&bufA[b][rA * GPITCH + hA * 32 + j * 8] = stA[j];
            *(bf16x8*)&bufB[b][rA * GPITCH + hA * 32 + j * 8] = stB[j];
        }
    };

    f32x4 acc[8][4] = {};

    const int nt = K / GBK;
    load_regs(0);
    write_lds(0);
    load_regs(GBK);

    for (int i = 0; i < nt; ++i) {
        const int c = i & 1;
        // raw barrier: prior ds ops drained; NO vmcnt(0) forced here, so the
        // 8 global loads issued last iteration stay in flight as needed.
        asm volatile("s_waitcnt lgkmcnt(0)\n\ts_barrier" ::: "memory");
        if (i + 1 < nt) write_lds(c ^ 1);         // vmcnt wait auto-inserted (regs old)
        if (i + 2 < nt) load_regs((i + 2) * GBK); // fly through compute below

        bf16x8 bh[4], bl[4];
        #pragma unroll
        for (int nf = 0; nf < 4; ++nf) {
            const int r = wn + nf * 16 + l15;
            bh[nf] = *(const bf16x8*)&bufB[c][r * GPITCH + kgr * 8];
            bl[nf] = *(const bf16x8*)&bufB[c][r * GPITCH + 32 + kgr * 8];
        }
        #pragma unroll
        for (int mf = 0; mf < 8; ++mf) {
            const int r = wm + mf * 16 + l15;
            bf16x8 ah = *(const bf16x8*)&bufA[c][r * GPITCH + kgr * 8];
            bf16x8 al = *(const bf16x8*)&bufA[c][r * GPITCH + 32 + kgr * 8];
            #pragma unroll
            for (int nf = 0; nf < 4; ++nf) {
                acc[mf][nf] = __builtin_amdgcn_mfma_f32_16x16x32_bf16(ah, bh[nf], acc[mf][nf], 0, 0, 0);
                acc[mf][nf] = __builtin_amdgcn_mfma_f32_16x16x32_bf16(ah, bl[nf], acc[mf][nf], 0, 0, 0);
                acc[mf][nf] = __builtin_amdgcn_mfma_f32_16x16x32_bf16(al, bh[nf], acc[mf][nf], 0, 0, 0);
            }
        }
    }

    #pragma unroll
    for (int mf = 0; mf < 8; ++mf)
        #pragma unroll
        for (int nf = 0; nf < 4; ++nf)
            #pragma unroll
            for (int r = 0; r < 4; ++r) {
                const int m = bm + wm + mf * 16 + kgr * 4 + r;
                const int n = bn + wn + nf * 16 + l15;
                const float v = acc[mf][nf][r];
                if constexpr (BF16OUT) {
                    ushort h = f2bf(v);
                    Ch[(size_t)m * N + n] = h;
                    Cl[(size_t)m * N + n] = f2bf(v - bf2f(h));
                } else {
                    Cf[(size_t)m * N + n] = v;
                }
            }
}

// ===========================================================================
// bf16x3 GEMM v1 (128x128, 4 waves) — kept for out-proj (256 blocks = full chip)
// ===========================================================================
template<bool BF16OUT>
__global__ __launch_bounds__(256, 2)
void gemm_bf16x3(const ushort* __restrict__ Ah_g, const ushort* __restrict__ Al_g,
                 const ushort* __restrict__ Bh_g, const ushort* __restrict__ Bl_g,
                 ushort* __restrict__ Ch, ushort* __restrict__ Cl,
                 float* __restrict__ Cf, int M, int N, int K)
{
    __shared__ ushort Ah[128 * 40], Al[128 * 40], Bh[128 * 40], Bl[128 * 40];
    const int t = threadIdx.x;
    const int l = t & 63;
    const int w = t >> 6;
    const int l15 = l & 15, kgr = l >> 4;
    const int wm = (w >> 1) * 64, wn = (w & 1) * 64;
    const int bm = blockIdx.y * 128, bn = blockIdx.x * 128;
    const int sr = t >> 2, sku = (t & 3) * 8;

    f32x4 acc[4][4] = {};
    bf16x8 sA[4], sB[4];

    auto load_stage = [&](int k0) {
        const size_t a0 = (size_t)(bm + sr) * K + k0 + sku;
        const size_t a1 = (size_t)(bm + sr + 64) * K + k0 + sku;
        sA[0] = *(const bf16x8*)(Ah_g + a0);
        sA[1] = *(const bf16x8*)(Ah_g + a1);
        sA[2] = *(const bf16x8*)(Al_g + a0);
        sA[3] = *(const bf16x8*)(Al_g + a1);
        const size_t b0 = (size_t)(bn + sr) * K + k0 + sku;
        const size_t b1 = (size_t)(bn + sr + 64) * K + k0 + sku;
        sB[0] = *(const bf16x8*)(Bh_g + b0);
        sB[1] = *(const bf16x8*)(Bh_g + b1);
        sB[2] = *(const bf16x8*)(Bl_g + b0);
        sB[3] = *(const bf16x8*)(Bl_g + b1);
    };
    auto write_stage = [&]() {
        *(bf16x8*)&Ah[sr * 40 + sku]        = sA[0];
        *(bf16x8*)&Ah[(sr + 64) * 40 + sku] = sA[1];
        *(bf16x8*)&Al[sr * 40 + sku]        = sA[2];
        *(bf16x8*)&Al[(sr + 64) * 40 + sku] = sA[3];
        *(bf16x8*)&Bh[sr * 40 + sku]        = sB[0];
        *(bf16x8*)&Bh[(sr + 64) * 40 + sku] = sB[1];
        *(bf16x8*)&Bl[sr * 40 + sku]        = sB[2];
        *(bf16x8*)&Bl[(sr + 64) * 40 + sku] = sB[3];
    };

    load_stage(0);
    for (int k0 = 0; k0 < K; k0 += 32) {
        __syncthreads();
        write_stage();
        __syncthreads();
        if (k0 + 32 < K) load_stage(k0 + 32);

        bf16x8 ah[4], al[4], bh[4], bl[4];
        #pragma unroll
        for (int mf = 0; mf < 4; ++mf) {
            ah[mf] = *(const bf16x8*)&Ah[(wm + mf * 16 + l15) * 40 + kgr * 8];
            al[mf] = *(const bf16x8*)&Al[(wm + mf * 16 + l15) * 40 + kgr * 8];
        }
        #pragma unroll
        for (int nf = 0; nf < 4; ++nf) {
            bh[nf] = *(const bf16x8*)&Bh[(wn + nf * 16 + l15) * 40 + kgr * 8];
            bl[nf] = *(const bf16x8*)&Bl[(wn + nf * 16 + l15) * 40 + kgr * 8];
        }
        #pragma unroll
        for (int mf = 0; mf < 4; ++mf)
            #pragma unroll
            for (int nf = 0; nf < 4; ++nf) {
                acc[mf][nf] = __builtin_amdgcn_mfma_f32_16x16x32_bf16(ah[mf], bh[nf], acc[mf][nf], 0, 0, 0);
                acc[mf][nf] = __builtin_amdgcn_mfma_f32_16x16x32_bf16(ah[mf], bl[nf], acc[mf][nf], 0, 0, 0);
                acc[mf][nf] = __builtin_amdgcn_mfma_f32_16x16x32_bf16(al[mf], bh[nf], acc[mf][nf], 0, 0, 0);
            }
    }

    #pragma unroll
    for (int mf = 0; mf < 4; ++mf)
        #pragma unroll
        for (int nf = 0; nf < 4; ++nf)
            #pragma unroll
            for (int r = 0; r < 4; ++r) {
                const int m = bm + wm + mf * 16 + kgr * 4 + r;
                const int n = bn + wn + nf * 16 + l15;
                const float v = acc[mf][nf][r];
                if constexpr (BF16OUT) {
                    ushort h = f2bf(v);
                    Ch[(size_t)m * N + n] = h;
                    Cl[(size_t)m * N + n] = f2bf(v - bf2f(h));
                } else {
                    Cf[(size_t)m * N + n] = v;
                }
            }
}

// ===========================================================================
// MFMA flash attention (unchanged from round 3 — passed, cost TBD in counters)
// ===========================================================================
__global__ __launch_bounds__(256, 2)
void attn_mfma(const ushort* __restrict__ qkvh, const ushort* __restrict__ qkvl,
               const ushort* __restrict__ vt,
               ushort* __restrict__ oh, ushort* __restrict__ ol)
{
    __shared__ ushort Kh[64 * 136], Kl[64 * 136], Vts[128 * 72], St[4 * 16 * 72];
    const int t = threadIdx.x;
    const int l = t & 63;
    const int w = t >> 6;
    const int l15 = l & 15, kgr = l >> 4;
    const int h = blockIdx.y, qb = blockIdx.x;
    const int q0 = qb * 64 + w * 16;

    bf16x8 qh[4], ql[4];
    {
        const size_t base = (size_t)(q0 + l15) * QKV_LD + h * HDIM;
        #pragma unroll
        for (int kc = 0; kc < 4; ++kc) {
            qh[kc] = *(const bf16x8*)(qkvh + base + kc * 32 + kgr * 8);
            ql[kc] = *(const bf16x8*)(qkvl + base + kc * 32 + kgr * 8);
        }
    }

    f32x4 o[8] = {};
    float m_run[4], l_run[4];
    #pragma unroll
    for (int r = 0; r < 4; ++r) { m_run[r] = -1e30f; l_run[r] = 0.f; }

    bf16x8 sKh[4], sKl[4], sV[4];
    auto load_tile = [&](int jb) {
        #pragma unroll
        for (int i = 0; i < 4; ++i) {
            int r = (t >> 4) + i * 16;
            size_t g = (size_t)(jb + r) * QKV_LD + DMODEL + h * HDIM + (t & 15) * 8;
            sKh[i] = *(const bf16x8*)(qkvh + g);
            sKl[i] = *(const bf16x8*)(qkvl + g);
        }
        #pragma unroll
        for (int i = 0; i < 4; ++i) {
            int d = (t >> 3) + i * 32;
            sV[i] = *(const bf16x8*)(vt + (size_t)(h * HDIM + d) * N_SEQ + jb + (t & 7) * 8);
        }
    };
    auto write_tile = [&]() {
        #pragma unroll
        for (int i = 0; i < 4; ++i) {
            int r = (t >> 4) + i * 16;
            *(bf16x8*)&Kh[r * 136 + (t & 15) * 8] = sKh[i];
            *(bf16x8*)&Kl[r * 136 + (t & 15) * 8] = sKl[i];
        }
        #pragma unroll
        for (int i = 0; i < 4; ++i) {
            int d = (t >> 3) + i * 32;
            *(bf16x8*)&Vts[d * 72 + (t & 7) * 8] = sV[i];
        }
    };

    const float scale = 0.08838834764831845f;  // 1/sqrt(128)

    load_tile(0);
    for (int jt = 0; jt <= qb; ++jt) {
        const int jb = jt * 64;
        __syncthreads();
        write_tile();
        __syncthreads();
        if (jt < qb) load_tile(jb + 64);

        float sv[4][4];
        #pragma unroll
        for (int jf = 0; jf < 4; ++jf) {
            f32x4 sacc = {};
            #pragma unroll
            for (int kc = 0; kc < 4; ++kc) {
                bf16x8 kh = *(const bf16x8*)&Kh[(jf * 16 + l15) * 136 + kc * 32 + kgr * 8];
                bf16x8 kl = *(const bf16x8*)&Kl[(jf * 16 + l15) * 136 + kc * 32 + kgr * 8];
                sacc = __builtin_amdgcn_mfma_f32_16x16x32_bf16(qh[kc], kh, sacc, 0, 0, 0);
                sacc = __builtin_amdgcn_mfma_f32_16x16x32_bf16(qh[kc], kl, sacc, 0, 0, 0);
                sacc = __builtin_amdgcn_mfma_f32_16x16x32_bf16(ql[kc], kh, sacc, 0, 0, 0);
            }
            const int j = jb + jf * 16 + l15;
            #pragma unroll
            for (int r = 0; r < 4; ++r) {
                const int q = q0 + kgr * 4 + r;
                sv[jf][r] = (j > q) ? -1e30f : sacc[r] * scale;
            }
        }

        float corr[4], p[4][4];
        #pragma unroll
        for (int r = 0; r < 4; ++r) {
            float tm = fmaxf(fmaxf(sv[0][r], sv[1][r]), fmaxf(sv[2][r], sv[3][r]));
            tm = fmaxf(tm, __shfl_xor(tm, 1));
            tm = fmaxf(tm, __shfl_xor(tm, 2));
            tm = fmaxf(tm, __shfl_xor(tm, 4));
            tm = fmaxf(tm, __shfl_xor(tm, 8));
            const float nm = fmaxf(m_run[r], tm);
            corr[r] = __expf(m_run[r] - nm);
            m_run[r] = nm;
            float rs = 0.f;
            #pragma unroll
            for (int jf = 0; jf < 4; ++jf) { p[jf][r] = __expf(sv[jf][r] - nm); rs += p[jf][r]; }
            rs += __shfl_xor(rs, 1);
            rs += __shfl_xor(rs, 2);
            rs += __shfl_xor(rs, 4);
            rs += __shfl_xor(rs, 8);
            l_run[r] = l_run[r] * corr[r] + rs;
        }

        #pragma unroll
        for (int jf = 0; jf < 4; ++jf)
            #pragma unroll
            for (int r = 0; r < 4; ++r)
                St[w * 1152 + (kgr * 4 + r) * 72 + jf * 16 + l15] = f2bf(p[jf][r]);

        #pragma unroll
        for (int df = 0; df < 8; ++df)
            #pragma unroll
            for (int r = 0; r < 4; ++r) o[df][r] *= corr[r];

        #pragma unroll
        for (int jc = 0; jc < 2; ++jc) {
            bf16x8 pa = *(const bf16x8*)&St[w * 1152 + l15 * 72 + jc * 32 + kgr * 8];
            #pragma unroll
            for (int df = 0; df < 8; ++df) {
                bf16x8 vb = *(const bf16x8*)&Vts[(df * 16 + l15) * 72 + jc * 32 + kgr * 8];
                o[df] = __builtin_amdgcn_mfma_f32_16x16x32_bf16(pa, vb, o[df], 0, 0, 0);
            }
        }
    }

    #pragma unroll
    for (int r = 0; r < 4; ++r) l_run[r] = 1.f / l_run[r];
    #pragma unroll
    for (int df = 0; df < 8; ++df)
        #pragma unroll
        for (int r = 0; r < 4; ++r) {
            const float v = o[df][r] * l_run[r];
            const size_t a = (size_t)(q0 + kgr * 4 + r) * DMODEL + h * HDIM + df * 16 + l15;
            const ushort hh = f2bf(v);
            oh[a] = hh;
            ol[a] = f2bf(v - bf2f(hh));
        }
}

// ===========================================================================
extern "C" void kernel_launch(void* const* d_in, const int* in_sizes, int n_in,
                              void* d_out, int out_size, void* d_ws, size_t ws_size,
                              hipStream_t stream)
{
    const float* x    = (const float*)d_in[0];
    const float* Wqkv = (const float*)d_in[1];
    const float* Wout = (const float*)d_in[2];
    float* outp = (float*)d_out;

    // ws layout (bytes):
    //  [0, 8M)       x_hi   -> later attn_hi
    //  [8M, 16M)     x_lo   -> later attn_lo
    //  [16M, 64M)    wqkvt hi/lo -> later woutt hi/lo + vt
    //  [64M, 112M)   qkv hi/lo
    const size_t O_XHI = 0;
    const size_t O_XLO = 8388608;
    const size_t O_WT  = 16777216;
    const size_t O_QKV = 67108864;

    char* ws = (char*)d_ws;
    ushort* x_hi   = (ushort*)(ws + O_XHI);
    ushort* x_lo   = (ushort*)(ws + O_XLO);
    ushort* wqt_hi = (ushort*)(ws + O_WT);
    ushort* wqt_lo = (ushort*)(ws + O_WT + 25165824);
    ushort* qkv_hi = (ushort*)(ws + O_QKV);
    ushort* qkv_lo = (ushort*)(ws + O_QKV + 25165824);
    // after GEMM1 these alias the (dead) wqkvt region:
    ushort* wot_hi = (ushort*)(ws + O_WT);
    ushort* wot_lo = (ushort*)(ws + O_WT + 8388608);
    ushort* vt     = (ushort*)(ws + O_WT + 16777216);
    // after GEMM1 these alias the (dead) x region:
    ushort* at_hi  = (ushort*)(ws + O_XHI);
    ushort* at_lo  = (ushort*)(ws + O_XLO);

    // 1. split x
    convert_split<<<dim3(N_SEQ * DMODEL / 4 / 256), 256, 0, stream>>>(
        x, x_hi, x_lo, N_SEQ * DMODEL / 4);
    // 2. split + transpose Wqkv -> [6144][2048]
    convert_split_t<<<dim3(QKV_LD / 64, DMODEL / 64), 256, 0, stream>>>(
        Wqkv, wqt_hi, wqt_lo, DMODEL, QKV_LD);
    // 3. qkv = x @ Wqkv  (bf16 hi/lo out) — new 256^2 single-barrier kernel
    gemm_bf16x3_v2<true><<<dim3(QKV_LD / GBN, N_SEQ / GBM), 512, 0, stream>>>(
        x_hi, x_lo, wqt_hi, wqt_lo, qkv_hi, qkv_lo, nullptr,
        N_SEQ, QKV_LD, DMODEL);
    // 4. split + transpose Wout -> [2048][2048]  (into dead wqkvt region)
    convert_split_t<<<dim3(DMODEL / 64, DMODEL / 64), 256, 0, stream>>>(
        Wout, wot_hi, wot_lo, DMODEL, DMODEL);
    // 5. transpose V (bf16 hi only)
    transpose_v<<<dim3(DMODEL / 64, N_SEQ / 64), 256, 0, stream>>>(qkv_hi, vt);
    // 6. attention (writes attn hi/lo into dead x region)
    attn_mfma<<<dim3(N_SEQ / 64, NHEAD), 256, 0, stream>>>(
        qkv_hi, qkv_lo, vt, at_hi, at_lo);
    // 7. out = attn @ Wout (fp32 out) — v1 kernel: 256 blocks = full chip
    gemm_bf16x3<false><<<dim3(DMODEL / 128, N_SEQ / 128), 256, 0, stream>>>(
        at_hi, at_lo, wot_hi, wot_lo, nullptr, nullptr, outp,
        N_SEQ, DMODEL, DMODEL);
}